// Round 1
// baseline (837.481 us; speedup 1.0000x reference)
//
#include <hip/hip_runtime.h>
#include <stdint.h>
#include <math.h>

typedef float f32x4 __attribute__((ext_vector_type(4)));
typedef __bf16 bf16x8_t __attribute__((ext_vector_type(8)));
typedef unsigned short us8 __attribute__((ext_vector_type(8)));
typedef unsigned short us4 __attribute__((ext_vector_type(4)));

__device__ __forceinline__ unsigned short f2bf(float f) {
  union { float f; uint32_t u; } v; v.f = f;
  uint32_t u = v.u;
  uint32_t r = (u + 0x7fffu + ((u >> 16) & 1u)) >> 16;
  return (unsigned short)r;
}
__device__ __forceinline__ float bf2f(unsigned short h) {
  union { uint32_t u; float f; } v; v.u = ((uint32_t)h) << 16;
  return v.f;
}
__device__ __forceinline__ f32x4 mfma16(us8 a, us8 b, f32x4 c) {
  return __builtin_amdgcn_mfma_f32_16x16x32_bf16(
      __builtin_bit_cast(bf16x8_t, a), __builtin_bit_cast(bf16x8_t, b), c, 0, 0, 0);
}

// ---------------- workspace layout (bytes) ----------------
// wft   bf16 [1024][2048]  @ 0          (4,194,304)
// wot   bf16 [1024][1024]  @ 4194304    (2,097,152)
// keysB bf16 [128][1024]   @ 6291456    (262,144)
// valT  bf16 [1024][128]   @ 6553600    (262,144)
// w1t   bf16 [128][1024]   @ 6815744    (262,144)
// w2t   bf16 [128][128]    @ 7077888    (32,768)
// stats1 f32 [32768][2]    @ 7110656    (262,144)
// stats2 f32 [32768][2]    @ 7372800    (262,144)
// union @ 7634944:
//   ww       bf16 [32768][128]   (8,388,608)
//   partials f32  [32][128][1024] @ +8388608 (16,777,216)
//   tb       bf16 [32768][1024]  (67,108,864)  (written after partials dead)
// total ws = 74,743,808 bytes
// d_out: [0,64MB)=mem_read bf16 ; [64MB,128MB)=f bf16 ; both overwritten by
// final LN2 f32 out [0,134MB); new_values f32 at element 33554432.

// ---------------- prep: cast/transpose weights, zero stats ----------------
__global__ __launch_bounds__(256) void k_prep(
    const float* __restrict__ keys, const float* __restrict__ values,
    const float* __restrict__ W1, const float* __restrict__ W2,
    const float* __restrict__ Wf, const float* __restrict__ Wo,
    unsigned short* __restrict__ wft, unsigned short* __restrict__ wot,
    unsigned short* __restrict__ keysB, unsigned short* __restrict__ valT,
    unsigned short* __restrict__ w1t, unsigned short* __restrict__ w2t,
    float* __restrict__ statsz)
{
  int i = blockIdx.x * 256 + threadIdx.x;
  if (i < 2097152) { int k = i >> 10, n = i & 1023; wft[n * 2048 + k] = f2bf(Wf[i]); return; }
  i -= 2097152;
  if (i < 1048576) { int k = i >> 10, n = i & 1023; wot[n * 1024 + k] = f2bf(Wo[i]); return; }
  i -= 1048576;
  if (i < 131072) { keysB[i] = f2bf(keys[i]); return; }
  i -= 131072;
  if (i < 131072) { int s = i >> 10, d = i & 1023; valT[d * 128 + s] = f2bf(values[i]); return; }
  i -= 131072;
  if (i < 131072) { int k = i >> 7, h = i & 127; w1t[h * 1024 + k] = f2bf(W1[i]); return; }
  i -= 131072;
  if (i < 16384) { int h = i >> 7, s = i & 127; w2t[s * 128 + h] = f2bf(W2[i]); return; }
  i -= 16384;
  if (i < 131072) { statsz[i] = 0.f; return; }
}

// ---------------- attention read + write-head (16 rows / block) -------------
__global__ __launch_bounds__(256) void k_attn(
    const float* __restrict__ x, const unsigned short* __restrict__ keysB,
    const unsigned short* __restrict__ valT, const unsigned short* __restrict__ w1t,
    const unsigned short* __restrict__ w2t, const float* __restrict__ b1,
    const float* __restrict__ b2, const float* __restrict__ temp,
    unsigned short* __restrict__ memread, unsigned short* __restrict__ ww)
{
  __shared__ unsigned short xq[16][1032];
  __shared__ float lg[16][132];
  __shared__ unsigned short at[16][136];
  __shared__ unsigned short hl[16][136];
  __shared__ float rowinv[16];

  int t = threadIdx.x;
  int row0 = blockIdx.x * 16;

  // x rows -> LDS bf16
  #pragma unroll
  for (int it = 0; it < 16; ++it) {
    f32x4 v = *(const f32x4*)(x + (size_t)(row0 + it) * 1024 + t * 4);
    us4 o; o[0] = f2bf(v[0]); o[1] = f2bf(v[1]); o[2] = f2bf(v[2]); o[3] = f2bf(v[3]);
    *(us4*)&xq[it][t * 4] = o;
  }
  __syncthreads();

  int w = t >> 6, l = t & 63, g = l >> 4, lc = l & 15;
  int q2 = w * 2;   // 16-wide col-tile base for G1/G3/G4

  // G1: logits = q@keys^T ; G3: q@W1 (fused K loop)
  f32x4 acc1[2] = {}; f32x4 acc3[2] = {};
  for (int ks = 0; ks < 32; ++ks) {
    us8 a = *(const us8*)&xq[lc][ks * 32 + g * 8];
    #pragma unroll
    for (int i = 0; i < 2; ++i) {
      int colr = (q2 + i) * 16 + lc;
      us8 bk = *(const us8*)(keysB + (size_t)colr * 1024 + ks * 32 + g * 8);
      acc1[i] = mfma16(a, bk, acc1[i]);
      us8 bw = *(const us8*)(w1t + (size_t)colr * 1024 + ks * 32 + g * 8);
      acc3[i] = mfma16(a, bw, acc3[i]);
    }
  }
  #pragma unroll
  for (int i = 0; i < 2; ++i) {
    int col = (q2 + i) * 16 + lc;
    float bb = b1[col];
    #pragma unroll
    for (int j = 0; j < 4; ++j) {
      int r = g * 4 + j;
      lg[r][col] = acc1[i][j];
      float v = acc3[i][j] + bb;
      v = 0.5f * v * (1.f + erff(v * 0.70710678118654752f)); // exact gelu
      hl[r][col] = f2bf(v);
    }
  }
  __syncthreads();

  // softmax over 128 slots (16 threads per row)
  {
    int r = t >> 4, sub = t & 15;
    float invt = 1.f / fmaxf(temp[0], 1e-6f);
    float vals[8]; float m = -3.4e38f;
    #pragma unroll
    for (int i = 0; i < 8; ++i) { vals[i] = lg[r][sub * 8 + i]; m = fmaxf(m, vals[i]); }
    m = fmaxf(m, __shfl_xor(m, 1)); m = fmaxf(m, __shfl_xor(m, 2));
    m = fmaxf(m, __shfl_xor(m, 4)); m = fmaxf(m, __shfl_xor(m, 8));
    float s = 0.f;
    #pragma unroll
    for (int i = 0; i < 8; ++i) {
      float e = __expf((vals[i] - m) * invt);
      s += e;
      at[r][sub * 8 + i] = f2bf(e);
    }
    s += __shfl_xor(s, 1); s += __shfl_xor(s, 2);
    s += __shfl_xor(s, 4); s += __shfl_xor(s, 8);
    if (sub == 0) rowinv[r] = 1.f / s;
  }
  __syncthreads();

  // G2: mem_read = (attn/sum) @ values
  {
    float ri[4];
    #pragma unroll
    for (int j = 0; j < 4; ++j) ri[j] = rowinv[g * 4 + j];
    f32x4 acc[16] = {};
    #pragma unroll
    for (int ks = 0; ks < 4; ++ks) {
      us8 a = *(const us8*)&at[lc][ks * 32 + g * 8];
      #pragma unroll
      for (int i = 0; i < 16; ++i) {
        int dt = w * 16 + i;
        us8 b = *(const us8*)(valT + (size_t)(dt * 16 + lc) * 128 + ks * 32 + g * 8);
        acc[i] = mfma16(a, b, acc[i]);
      }
    }
    #pragma unroll
    for (int i = 0; i < 16; ++i) {
      int dt = w * 16 + i;
      #pragma unroll
      for (int j = 0; j < 4; ++j) {
        int r = row0 + g * 4 + j;
        memread[(size_t)r * 1024 + dt * 16 + lc] = f2bf(acc[i][j] * ri[j]);
      }
    }
  }

  // G4: ww = sigmoid(h@W2 + b2)
  {
    f32x4 acc[2] = {};
    #pragma unroll
    for (int ks = 0; ks < 4; ++ks) {
      us8 a = *(const us8*)&hl[lc][ks * 32 + g * 8];
      #pragma unroll
      for (int i = 0; i < 2; ++i) {
        us8 b = *(const us8*)(w2t + (size_t)((q2 + i) * 16 + lc) * 128 + ks * 32 + g * 8);
        acc[i] = mfma16(a, b, acc[i]);
      }
    }
    #pragma unroll
    for (int i = 0; i < 2; ++i) {
      int col = (q2 + i) * 16 + lc;
      float bb = b2[col];
      #pragma unroll
      for (int j = 0; j < 4; ++j) {
        int r = row0 + g * 4 + j;
        float v = acc[i][j] + bb;
        v = 1.f / (1.f + __expf(-v));
        ww[(size_t)r * 128 + col] = f2bf(v);
      }
    }
  }
}

// ---------------- ww^T @ q  (partials per n-chunk) ----------------
__global__ __launch_bounds__(256) void k_wv(
    const float* __restrict__ x, const unsigned short* __restrict__ ww,
    float* __restrict__ partials)
{
  __shared__ unsigned short wwT[128][40];
  __shared__ unsigned short xT[128][40];
  int t = threadIdx.x;
  int chunk = blockIdx.x >> 3;
  int dt0 = (blockIdx.x & 7) * 128;
  int w = t >> 6, l = t & 63, g = l >> 4, lc = l & 15;
  f32x4 acc[2][8] = {};
  int nn = t >> 3, e0 = (t & 7) * 16;

  for (int ks = 0; ks < 32; ++ks) {
    int n0 = chunk * 1024 + ks * 32;
    __syncthreads();
    {
      us8 v0 = *(const us8*)(ww + (size_t)(n0 + nn) * 128 + e0);
      us8 v1 = *(const us8*)(ww + (size_t)(n0 + nn) * 128 + e0 + 8);
      #pragma unroll
      for (int i = 0; i < 8; ++i) { wwT[e0 + i][nn] = v0[i]; wwT[e0 + 8 + i][nn] = v1[i]; }
      const float* xp = x + (size_t)(n0 + nn) * 1024 + dt0 + e0;
      #pragma unroll
      for (int q = 0; q < 4; ++q) {
        f32x4 xv = *(const f32x4*)(xp + q * 4);
        #pragma unroll
        for (int j = 0; j < 4; ++j) xT[e0 + q * 4 + j][nn] = f2bf(xv[j]);
      }
    }
    __syncthreads();
    us8 bfr[8];
    #pragma unroll
    for (int i = 0; i < 8; ++i) bfr[i] = *(const us8*)&xT[i * 16 + lc][g * 8];
    #pragma unroll
    for (int st = 0; st < 2; ++st) {
      us8 a = *(const us8*)&wwT[(w * 2 + st) * 16 + lc][g * 8];
      #pragma unroll
      for (int i = 0; i < 8; ++i) acc[st][i] = mfma16(a, bfr[i], acc[st][i]);
    }
  }
  float* p = partials + (size_t)chunk * 131072;
  #pragma unroll
  for (int st = 0; st < 2; ++st)
    #pragma unroll
    for (int i = 0; i < 8; ++i)
      #pragma unroll
      for (int j = 0; j < 4; ++j) {
        int s = (w * 2 + st) * 16 + g * 4 + j;
        p[s * 1024 + dt0 + i * 16 + lc] = acc[st][i][j];
      }
}

__global__ __launch_bounds__(256) void k_red(
    const float* __restrict__ values, const float* __restrict__ partials,
    float* __restrict__ outv)
{
  int i = blockIdx.x * 256 + threadIdx.x;
  float s = 0.f;
  #pragma unroll
  for (int c = 0; c < 32; ++c) s += partials[(size_t)c * 131072 + i];
  outv[i] = values[i] + 0.1f * s;
}

// ---------------- GEMM-F: f = [x|mem_read]@Wf + bf (+row stats) -------------
__global__ __launch_bounds__(256) void k_gemm_f(
    const float* __restrict__ x, const unsigned short* __restrict__ memread,
    const unsigned short* __restrict__ wft, const float* __restrict__ bfp,
    unsigned short* __restrict__ f, float* __restrict__ stats1)
{
  __shared__ unsigned short Al[2][128][40];
  __shared__ unsigned short Bl[2][128][40];
  int t = threadIdx.x;
  int m0 = (blockIdx.x >> 3) * 128;
  int n0 = (blockIdx.x & 7) * 128;
  int w = t >> 6, l = t & 63, g = l >> 4, lc = l & 15;
  int wm = w >> 1, wn = w & 1;
  int srow = t >> 1, skp = (t & 1) * 16;

  f32x4 acc[4][4] = {};
  us8 ra0, ra1, rb0, rb1;

  auto load_stage = [&](int ks) {
    int k0 = ks * 32 + skp;
    if (k0 < 1024) {
      const float* xp = x + (size_t)(m0 + srow) * 1024 + k0;
      f32x4 v0 = ((const f32x4*)xp)[0], v1 = ((const f32x4*)xp)[1],
            v2 = ((const f32x4*)xp)[2], v3 = ((const f32x4*)xp)[3];
      #pragma unroll
      for (int e = 0; e < 4; ++e) {
        ra0[e] = f2bf(v0[e]); ra0[e + 4] = f2bf(v1[e]);
        ra1[e] = f2bf(v2[e]); ra1[e + 4] = f2bf(v3[e]);
      }
    } else {
      const us8* mp = (const us8*)(memread + (size_t)(m0 + srow) * 1024 + (k0 - 1024));
      ra0 = mp[0]; ra1 = mp[1];
    }
    const us8* bp = (const us8*)(wft + (size_t)(n0 + srow) * 2048 + k0);
    rb0 = bp[0]; rb1 = bp[1];
  };
  auto write_stage = [&](int buf) {
    *(us8*)&Al[buf][srow][skp] = ra0; *(us8*)&Al[buf][srow][skp + 8] = ra1;
    *(us8*)&Bl[buf][srow][skp] = rb0; *(us8*)&Bl[buf][srow][skp + 8] = rb1;
  };

  load_stage(0); write_stage(0);
  __syncthreads();
  int cur = 0;
  for (int ks = 0; ks < 64; ++ks) {
    if (ks + 1 < 64) load_stage(ks + 1);
    us8 a[4], b[4];
    #pragma unroll
    for (int i = 0; i < 4; ++i) a[i] = *(const us8*)&Al[cur][wm * 64 + i * 16 + lc][g * 8];
    #pragma unroll
    for (int j = 0; j < 4; ++j) b[j] = *(const us8*)&Bl[cur][wn * 64 + j * 16 + lc][g * 8];
    #pragma unroll
    for (int i = 0; i < 4; ++i)
      #pragma unroll
      for (int j = 0; j < 4; ++j)
        acc[i][j] = mfma16(a[i], b[j], acc[i][j]);
    if (ks + 1 < 64) write_stage(cur ^ 1);
    __syncthreads();
    cur ^= 1;
  }

  float bfv[4];
  #pragma unroll
  for (int jn = 0; jn < 4; ++jn) bfv[jn] = bfp[n0 + wn * 64 + jn * 16 + lc];
  #pragma unroll
  for (int i = 0; i < 4; ++i) {
    #pragma unroll
    for (int j = 0; j < 4; ++j) {
      int row = m0 + wm * 64 + i * 16 + g * 4 + j;
      float ssum = 0.f, ssq = 0.f;
      #pragma unroll
      for (int jn = 0; jn < 4; ++jn) {
        int col = n0 + wn * 64 + jn * 16 + lc;
        float v = acc[i][jn][j] + bfv[jn];
        f[(size_t)row * 1024 + col] = f2bf(v);
        ssum += v; ssq += v * v;
      }
      #pragma unroll
      for (int msk = 1; msk < 16; msk <<= 1) {
        ssum += __shfl_xor(ssum, msk); ssq += __shfl_xor(ssq, msk);
      }
      if (lc == 0) { atomicAdd(&stats1[row * 2], ssum); atomicAdd(&stats1[row * 2 + 1], ssq); }
    }
  }
}

// ---------------- GEMM-O: t = LN1(f)@Wo + bo + x (+row stats) ---------------
__global__ __launch_bounds__(256) void k_gemm_o(
    const unsigned short* __restrict__ f, const float* __restrict__ stats1,
    const float* __restrict__ ln1g, const float* __restrict__ ln1b,
    const unsigned short* __restrict__ wot, const float* __restrict__ bo,
    const float* __restrict__ x, unsigned short* __restrict__ tb,
    float* __restrict__ stats2)
{
  __shared__ unsigned short Al[2][128][40];
  __shared__ unsigned short Bl[2][128][40];
  int t = threadIdx.x;
  int m0 = (blockIdx.x >> 3) * 128;
  int n0 = (blockIdx.x & 7) * 128;
  int w = t >> 6, l = t & 63, g = l >> 4, lc = l & 15;
  int wm = w >> 1, wn = w & 1;
  int srow = t >> 1, skp = (t & 1) * 16;

  int grow = m0 + srow;
  float sA = stats1[grow * 2], sB = stats1[grow * 2 + 1];
  float mu = sA * (1.f / 1024.f);
  float rs = rsqrtf(sB * (1.f / 1024.f) - mu * mu + 1e-5f);

  f32x4 acc[4][4] = {};
  us8 ra0, ra1, rb0, rb1;

  auto load_stage = [&](int ks) {
    int k0 = ks * 32 + skp;
    us8 f0 = *(const us8*)(f + (size_t)grow * 1024 + k0);
    us8 f1 = *(const us8*)(f + (size_t)grow * 1024 + k0 + 8);
    float ga[16], ba[16];
    *(f32x4*)&ga[0] = *(const f32x4*)(ln1g + k0);
    *(f32x4*)&ga[4] = *(const f32x4*)(ln1g + k0 + 4);
    *(f32x4*)&ga[8] = *(const f32x4*)(ln1g + k0 + 8);
    *(f32x4*)&ga[12] = *(const f32x4*)(ln1g + k0 + 12);
    *(f32x4*)&ba[0] = *(const f32x4*)(ln1b + k0);
    *(f32x4*)&ba[4] = *(const f32x4*)(ln1b + k0 + 4);
    *(f32x4*)&ba[8] = *(const f32x4*)(ln1b + k0 + 8);
    *(f32x4*)&ba[12] = *(const f32x4*)(ln1b + k0 + 12);
    #pragma unroll
    for (int e = 0; e < 8; ++e) {
      ra0[e] = f2bf((bf2f(f0[e]) - mu) * rs * ga[e] + ba[e]);
      ra1[e] = f2bf((bf2f(f1[e]) - mu) * rs * ga[e + 8] + ba[e + 8]);
    }
    const us8* bp = (const us8*)(wot + (size_t)(n0 + srow) * 1024 + k0);
    rb0 = bp[0]; rb1 = bp[1];
  };
  auto write_stage = [&](int buf) {
    *(us8*)&Al[buf][srow][skp] = ra0; *(us8*)&Al[buf][srow][skp + 8] = ra1;
    *(us8*)&Bl[buf][srow][skp] = rb0; *(us8*)&Bl[buf][srow][skp + 8] = rb1;
  };

  load_stage(0); write_stage(0);
  __syncthreads();
  int cur = 0;
  for (int ks = 0; ks < 32; ++ks) {
    if (ks + 1 < 32) load_stage(ks + 1);
    us8 a[4], b[4];
    #pragma unroll
    for (int i = 0; i < 4; ++i) a[i] = *(const us8*)&Al[cur][wm * 64 + i * 16 + lc][g * 8];
    #pragma unroll
    for (int j = 0; j < 4; ++j) b[j] = *(const us8*)&Bl[cur][wn * 64 + j * 16 + lc][g * 8];
    #pragma unroll
    for (int i = 0; i < 4; ++i)
      #pragma unroll
      for (int j = 0; j < 4; ++j)
        acc[i][j] = mfma16(a[i], b[j], acc[i][j]);
    if (ks + 1 < 32) write_stage(cur ^ 1);
    __syncthreads();
    cur ^= 1;
  }

  float bov[4];
  #pragma unroll
  for (int jn = 0; jn < 4; ++jn) bov[jn] = bo[n0 + wn * 64 + jn * 16 + lc];
  #pragma unroll
  for (int i = 0; i < 4; ++i) {
    #pragma unroll
    for (int j = 0; j < 4; ++j) {
      int row = m0 + wm * 64 + i * 16 + g * 4 + j;
      float ssum = 0.f, ssq = 0.f;
      #pragma unroll
      for (int jn = 0; jn < 4; ++jn) {
        int col = n0 + wn * 64 + jn * 16 + lc;
        float v = acc[i][jn][j] + bov[jn] + x[(size_t)row * 1024 + col];
        tb[(size_t)row * 1024 + col] = f2bf(v);
        ssum += v; ssq += v * v;
      }
      #pragma unroll
      for (int msk = 1; msk < 16; msk <<= 1) {
        ssum += __shfl_xor(ssum, msk); ssq += __shfl_xor(ssq, msk);
      }
      if (lc == 0) { atomicAdd(&stats2[row * 2], ssum); atomicAdd(&stats2[row * 2 + 1], ssq); }
    }
  }
}

// ---------------- final LN2 ----------------
__global__ __launch_bounds__(256) void k_ln2(
    const unsigned short* __restrict__ tb, const float* __restrict__ stats2,
    const float* __restrict__ ln2g, const float* __restrict__ ln2b,
    float* __restrict__ out)
{
  size_t idx = ((size_t)blockIdx.x * 256 + threadIdx.x) * 8;
  int row = (int)(idx >> 10);
  int col = (int)(idx & 1023);
  float sA = stats2[row * 2], sB = stats2[row * 2 + 1];
  float mu = sA * (1.f / 1024.f);
  float rs = rsqrtf(sB * (1.f / 1024.f) - mu * mu + 1e-5f);
  us8 tv = *(const us8*)(tb + idx);
  f32x4 g0 = *(const f32x4*)(ln2g + col), g1 = *(const f32x4*)(ln2g + col + 4);
  f32x4 b0 = *(const f32x4*)(ln2b + col), b1v = *(const f32x4*)(ln2b + col + 4);
  f32x4 o0, o1;
  #pragma unroll
  for (int e = 0; e < 4; ++e) {
    o0[e] = (bf2f(tv[e]) - mu) * rs * g0[e] + b0[e];
    o1[e] = (bf2f(tv[e + 4]) - mu) * rs * g1[e] + b1v[e];
  }
  *(f32x4*)(out + idx) = o0;
  *(f32x4*)(out + idx + 4) = o1;
}

extern "C" void kernel_launch(void* const* d_in, const int* in_sizes, int n_in,
                              void* d_out, int out_size, void* d_ws, size_t ws_size,
                              hipStream_t stream) {
  const float* x      = (const float*)d_in[0];
  const float* keys   = (const float*)d_in[1];
  const float* values = (const float*)d_in[2];
  const float* temp   = (const float*)d_in[3];
  const float* W1     = (const float*)d_in[4];
  const float* b1     = (const float*)d_in[5];
  const float* W2     = (const float*)d_in[6];
  const float* b2     = (const float*)d_in[7];
  const float* Wf     = (const float*)d_in[8];
  const float* bfp    = (const float*)d_in[9];
  const float* ln1g   = (const float*)d_in[10];
  const float* ln1b   = (const float*)d_in[11];
  const float* Wo     = (const float*)d_in[12];
  const float* bo     = (const float*)d_in[13];
  const float* ln2g   = (const float*)d_in[14];
  const float* ln2b   = (const float*)d_in[15];

  char* ws = (char*)d_ws;
  unsigned short* wft   = (unsigned short*)(ws + 0);
  unsigned short* wot   = (unsigned short*)(ws + 4194304);
  unsigned short* keysB = (unsigned short*)(ws + 6291456);
  unsigned short* valT  = (unsigned short*)(ws + 6553600);
  unsigned short* w1t   = (unsigned short*)(ws + 6815744);
  unsigned short* w2t   = (unsigned short*)(ws + 7077888);
  float* stats1         = (float*)(ws + 7110656);
  float* stats2         = (float*)(ws + 7372800);
  unsigned short* ww    = (unsigned short*)(ws + 7634944);
  float* partials       = (float*)(ws + 7634944 + 8388608);
  unsigned short* tb    = (unsigned short*)(ws + 7634944);  // aliases ww+partials (dead by then)

  float* out = (float*)d_out;
  unsigned short* memread = (unsigned short*)d_out;                      // [0, 64MB)
  unsigned short* fb = (unsigned short*)((char*)d_out + 67108864);       // [64MB, 128MB)
  float* newvals = out + 33554432;

  k_prep<<<14400, 256, 0, stream>>>(keys, values, W1, W2, Wf, Wo,
                                    wft, wot, keysB, valT, w1t, w2t, stats1);
  k_attn<<<2048, 256, 0, stream>>>(x, keysB, valT, w1t, w2t, b1, b2, temp, memread, ww);
  k_wv<<<256, 256, 0, stream>>>(x, ww, partials);
  k_red<<<512, 256, 0, stream>>>(values, partials, newvals);
  k_gemm_f<<<2048, 256, 0, stream>>>(x, memread, wft, bfp, fb, stats1);
  k_gemm_o<<<2048, 256, 0, stream>>>(fb, stats1, ln1g, ln1b, wot, bo, x, tb, stats2);
  k_ln2<<<16384, 256, 0, stream>>>(tb, stats2, ln2g, ln2b, out);
}

// Round 2
// 763.376 us; speedup vs baseline: 1.0971x; 1.0971x over previous
//
#include <hip/hip_runtime.h>
#include <stdint.h>
#include <math.h>

typedef float f32x4 __attribute__((ext_vector_type(4)));
typedef __bf16 bf16x8_t __attribute__((ext_vector_type(8)));
typedef unsigned short us8 __attribute__((ext_vector_type(8)));
typedef unsigned short us4 __attribute__((ext_vector_type(4)));
typedef unsigned int u32;

__device__ __forceinline__ unsigned short f2bf(float f) {
  union { float f; uint32_t u; } v; v.f = f;
  uint32_t u = v.u;
  uint32_t r = (u + 0x7fffu + ((u >> 16) & 1u)) >> 16;
  return (unsigned short)r;
}
__device__ __forceinline__ float bf2f(unsigned short h) {
  union { uint32_t u; float f; } v; v.u = ((uint32_t)h) << 16;
  return v.f;
}
__device__ __forceinline__ f32x4 mfma16(us8 a, us8 b, f32x4 c) {
  return __builtin_amdgcn_mfma_f32_16x16x32_bf16(
      __builtin_bit_cast(bf16x8_t, a), __builtin_bit_cast(bf16x8_t, b), c, 0, 0, 0);
}
__device__ __forceinline__ void gl16(const void* g, void* l) {
  __builtin_amdgcn_global_load_lds(
      (const __attribute__((address_space(1))) u32*)g,
      (__attribute__((address_space(3))) u32*)l, 16, 0, 0);
}

// ================= memory plan =================
// d_out (134,742,016 B):
//   xcat bf16 [32768][2048] @ 0           (cols 0-1023 = x bf16, 1024-2047 = mem_read)
//   -> dead after k_gemm_f; k_gemm_o writes t f32 [32768][1024] @ 0; k_ln2 in-place
//   new_values f32 [131072] @ 134217728   (never aliased)
// d_ws:
//   wft bf16 [1024][2048] @ 0
//   wot bf16 [1024][1024] @ 4194304
//   keysB bf16 [128][1024] @ 6291456
//   valT  bf16 [1024][128] @ 6553600
//   w1t   bf16 [128][1024] @ 6815744
//   w2t   bf16 [128][128]  @ 7077888
//   stats1 f32 [32768][2]  @ 7110656
//   stats2 f32 [32768][2]  @ 7372800
//   @7634944: ww bf16 [32768][128] (8MB) ; partials f32 [32][128][1024] @ +8MB
//             both dead before k_gemm_f -> fb bf16 [32768][1024] @ 7634944 (64MB)
//   total 74,743,808 B (same as round-0 footprint)

// ---------------- prep: weights cast/transpose + zero stats ----------------
__global__ __launch_bounds__(256) void k_prep(
    const float* __restrict__ keys, const float* __restrict__ W1,
    const float* __restrict__ W2, const float* __restrict__ Wf,
    const float* __restrict__ Wo, const float* __restrict__ values,
    unsigned short* __restrict__ wft, unsigned short* __restrict__ wot,
    unsigned short* __restrict__ keysB, unsigned short* __restrict__ valT,
    unsigned short* __restrict__ w1t, unsigned short* __restrict__ w2t,
    float* __restrict__ statsz)
{
  int i = blockIdx.x * 256 + threadIdx.x;
  if (i < 2097152) { int k = i >> 10, n = i & 1023; wft[n * 2048 + k] = f2bf(Wf[i]); return; }
  i -= 2097152;
  if (i < 1048576) { int k = i >> 10, n = i & 1023; wot[n * 1024 + k] = f2bf(Wo[i]); return; }
  i -= 1048576;
  if (i < 131072) { keysB[i] = f2bf(keys[i]); return; }
  i -= 131072;
  if (i < 131072) { int s = i >> 10, d = i & 1023; valT[d * 128 + s] = f2bf(values[i]); return; }
  i -= 131072;
  if (i < 131072) { int k = i >> 7, h = i & 127; w1t[h * 1024 + k] = f2bf(W1[i]); return; }
  i -= 131072;
  if (i < 16384) { int h = i >> 7, s = i & 127; w2t[s * 128 + h] = f2bf(W2[i]); return; }
  i -= 16384;
  if (i < 131072) { statsz[i] = 0.f; return; }
}

// ---------------- cast x f32 -> xcat cols [0,1024) bf16 ----------------
__global__ __launch_bounds__(256) void k_castx(
    const float* __restrict__ x, unsigned short* __restrict__ xcat)
{
  size_t idx = ((size_t)blockIdx.x * 256 + threadIdx.x) * 8;
  int row = (int)(idx >> 10), col = (int)(idx & 1023);
  f32x4 v0 = *(const f32x4*)(x + idx);
  f32x4 v1 = *(const f32x4*)(x + idx + 4);
  us8 o;
  #pragma unroll
  for (int e = 0; e < 4; ++e) { o[e] = f2bf(v0[e]); o[e + 4] = f2bf(v1[e]); }
  *(us8*)(xcat + (size_t)row * 2048 + col) = o;
}

// ---------------- attention read + write-head (16 rows / block) -------------
__global__ __launch_bounds__(256) void k_attn(
    const unsigned short* __restrict__ xcat, const unsigned short* __restrict__ keysB,
    const unsigned short* __restrict__ valT, const unsigned short* __restrict__ w1t,
    const unsigned short* __restrict__ w2t, const float* __restrict__ b1,
    const float* __restrict__ b2, const float* __restrict__ temp,
    unsigned short* __restrict__ xcat_mr, unsigned short* __restrict__ ww)
{
  __shared__ unsigned short xq[16][1032];
  __shared__ float lg[16][132];
  __shared__ unsigned short at[16][136];
  __shared__ unsigned short hl[16][136];
  __shared__ float rowinv[16];

  int t = threadIdx.x;
  int row0 = blockIdx.x * 16;

  // x rows (bf16, from xcat cols 0-1023) -> LDS
  {
    int r = t >> 4, c0 = (t & 15) * 64;
    const unsigned short* xp = xcat + (size_t)(row0 + r) * 2048 + c0;
    #pragma unroll
    for (int i = 0; i < 8; ++i)
      *(us8*)&xq[r][c0 + i * 8] = *(const us8*)(xp + i * 8);
  }
  __syncthreads();

  int w = t >> 6, l = t & 63, g = l >> 4, lc = l & 15;
  int q2 = w * 2;

  f32x4 acc1[2] = {}; f32x4 acc3[2] = {};
  for (int ks = 0; ks < 32; ++ks) {
    us8 a = *(const us8*)&xq[lc][ks * 32 + g * 8];
    #pragma unroll
    for (int i = 0; i < 2; ++i) {
      int colr = (q2 + i) * 16 + lc;
      us8 bk = *(const us8*)(keysB + (size_t)colr * 1024 + ks * 32 + g * 8);
      acc1[i] = mfma16(a, bk, acc1[i]);
      us8 bw = *(const us8*)(w1t + (size_t)colr * 1024 + ks * 32 + g * 8);
      acc3[i] = mfma16(a, bw, acc3[i]);
    }
  }
  #pragma unroll
  for (int i = 0; i < 2; ++i) {
    int col = (q2 + i) * 16 + lc;
    float bb = b1[col];
    #pragma unroll
    for (int j = 0; j < 4; ++j) {
      int r = g * 4 + j;
      lg[r][col] = acc1[i][j];
      float v = acc3[i][j] + bb;
      v = 0.5f * v * (1.f + erff(v * 0.70710678118654752f));
      hl[r][col] = f2bf(v);
    }
  }
  __syncthreads();

  {
    int r = t >> 4, sub = t & 15;
    float invt = 1.f / fmaxf(temp[0], 1e-6f);
    float vals[8]; float m = -3.4e38f;
    #pragma unroll
    for (int i = 0; i < 8; ++i) { vals[i] = lg[r][sub * 8 + i]; m = fmaxf(m, vals[i]); }
    m = fmaxf(m, __shfl_xor(m, 1)); m = fmaxf(m, __shfl_xor(m, 2));
    m = fmaxf(m, __shfl_xor(m, 4)); m = fmaxf(m, __shfl_xor(m, 8));
    float s = 0.f;
    #pragma unroll
    for (int i = 0; i < 8; ++i) {
      float e = __expf((vals[i] - m) * invt);
      s += e;
      at[r][sub * 8 + i] = f2bf(e);
    }
    s += __shfl_xor(s, 1); s += __shfl_xor(s, 2);
    s += __shfl_xor(s, 4); s += __shfl_xor(s, 8);
    if (sub == 0) rowinv[r] = 1.f / s;
  }
  __syncthreads();

  // mem_read -> xcat cols [1024,2048)
  {
    float ri[4];
    #pragma unroll
    for (int j = 0; j < 4; ++j) ri[j] = rowinv[g * 4 + j];
    f32x4 acc[16] = {};
    #pragma unroll
    for (int ks = 0; ks < 4; ++ks) {
      us8 a = *(const us8*)&at[lc][ks * 32 + g * 8];
      #pragma unroll
      for (int i = 0; i < 16; ++i) {
        int dt = w * 16 + i;
        us8 b = *(const us8*)(valT + (size_t)(dt * 16 + lc) * 128 + ks * 32 + g * 8);
        acc[i] = mfma16(a, b, acc[i]);
      }
    }
    #pragma unroll
    for (int i = 0; i < 16; ++i) {
      int dt = w * 16 + i;
      #pragma unroll
      for (int j = 0; j < 4; ++j) {
        int r = row0 + g * 4 + j;
        xcat_mr[(size_t)r * 2048 + 1024 + dt * 16 + lc] = f2bf(acc[i][j] * ri[j]);
      }
    }
  }

  // ww = sigmoid(h@W2 + b2)
  {
    f32x4 acc[2] = {};
    #pragma unroll
    for (int ks = 0; ks < 4; ++ks) {
      us8 a = *(const us8*)&hl[lc][ks * 32 + g * 8];
      #pragma unroll
      for (int i = 0; i < 2; ++i) {
        us8 b = *(const us8*)(w2t + (size_t)((q2 + i) * 16 + lc) * 128 + ks * 32 + g * 8);
        acc[i] = mfma16(a, b, acc[i]);
      }
    }
    #pragma unroll
    for (int i = 0; i < 2; ++i) {
      int col = (q2 + i) * 16 + lc;
      float bb = b2[col];
      #pragma unroll
      for (int j = 0; j < 4; ++j) {
        int r = row0 + g * 4 + j;
        float v = acc[i][j] + bb;
        v = 1.f / (1.f + __expf(-v));
        ww[(size_t)r * 128 + col] = f2bf(v);
      }
    }
  }
}

// ---------------- ww^T @ x  (partials per n-chunk) ----------------
__global__ __launch_bounds__(256) void k_wv(
    const unsigned short* __restrict__ xcat, const unsigned short* __restrict__ ww,
    float* __restrict__ partials)
{
  __shared__ unsigned short wwT[128][40];
  __shared__ unsigned short xT[128][40];
  int t = threadIdx.x;
  int chunk = blockIdx.x >> 3;
  int dt0 = (blockIdx.x & 7) * 128;
  int w = t >> 6, l = t & 63, g = l >> 4, lc = l & 15;
  f32x4 acc[2][8] = {};
  int nn = t >> 3, e0 = (t & 7) * 16;

  for (int ks = 0; ks < 32; ++ks) {
    int n0 = chunk * 1024 + ks * 32;
    __syncthreads();
    {
      us8 v0 = *(const us8*)(ww + (size_t)(n0 + nn) * 128 + e0);
      us8 v1 = *(const us8*)(ww + (size_t)(n0 + nn) * 128 + e0 + 8);
      #pragma unroll
      for (int i = 0; i < 8; ++i) { wwT[e0 + i][nn] = v0[i]; wwT[e0 + 8 + i][nn] = v1[i]; }
      const unsigned short* xp = xcat + (size_t)(n0 + nn) * 2048 + dt0 + e0;
      us8 x0 = *(const us8*)xp;
      us8 x1 = *(const us8*)(xp + 8);
      #pragma unroll
      for (int i = 0; i < 8; ++i) { xT[e0 + i][nn] = x0[i]; xT[e0 + 8 + i][nn] = x1[i]; }
    }
    __syncthreads();
    us8 bfr[8];
    #pragma unroll
    for (int i = 0; i < 8; ++i) bfr[i] = *(const us8*)&xT[i * 16 + lc][g * 8];
    #pragma unroll
    for (int st = 0; st < 2; ++st) {
      us8 a = *(const us8*)&wwT[(w * 2 + st) * 16 + lc][g * 8];
      #pragma unroll
      for (int i = 0; i < 8; ++i) acc[st][i] = mfma16(a, bfr[i], acc[st][i]);
    }
  }
  float* p = partials + (size_t)chunk * 131072;
  #pragma unroll
  for (int st = 0; st < 2; ++st)
    #pragma unroll
    for (int i = 0; i < 8; ++i)
      #pragma unroll
      for (int j = 0; j < 4; ++j) {
        int s = (w * 2 + st) * 16 + g * 4 + j;
        p[s * 1024 + dt0 + i * 16 + lc] = acc[st][i][j];
      }
}

__global__ __launch_bounds__(256) void k_red(
    const float* __restrict__ values, const float* __restrict__ partials,
    float* __restrict__ outv)
{
  int i = blockIdx.x * 256 + threadIdx.x;
  float s = 0.f;
  #pragma unroll
  for (int c = 0; c < 32; ++c) s += partials[(size_t)c * 131072 + i];
  outv[i] = values[i] + 0.1f * s;
}

// ---------------- m97-style 128x128 GEMM, glds staging, swizzled reads ------
// EPI 0: out = bf16(acc + bias) -> outF ; stats atomics
// EPI 1: out = f32(acc + bias + resid) -> outO ; stats atomics
template<int KTOT, int EPI>
__global__ __launch_bounds__(256) void k_gemm(
    const unsigned short* __restrict__ A, const unsigned short* __restrict__ B,
    const float* __restrict__ bias, unsigned short* __restrict__ outF,
    float* __restrict__ outO, const float* __restrict__ resid,
    float* __restrict__ stats)
{
  __shared__ __align__(16) unsigned short Al[4096];  // [128 rows][32 k] linear
  __shared__ __align__(16) unsigned short Bl[4096];

  int t = threadIdx.x;
  int bid = blockIdx.x;
  int cpx = gridDim.x >> 3;
  int logical = (bid & 7) * cpx + (bid >> 3);   // XCD-contiguous tiles
  int m0 = (logical >> 3) * 128, n0 = (logical & 7) * 128;

  // staging: thread t -> row t>>2 (and +64), k-slot (t&3)^(row&3) pre-swizzled
  int r = t >> 2, s = t & 3, sp = s ^ (r & 3);
  const unsigned short* ga = A + (size_t)(m0 + r) * KTOT + sp * 8;
  const unsigned short* gb = B + (size_t)(n0 + r) * KTOT + sp * 8;
  const unsigned short* ga2 = ga + (size_t)64 * KTOT;
  const unsigned short* gb2 = gb + (size_t)64 * KTOT;
  unsigned short* la  = Al + t * 8;
  unsigned short* la2 = Al + 2048 + t * 8;
  unsigned short* lb  = Bl + t * 8;
  unsigned short* lb2 = Bl + 2048 + t * 8;

  int w = t >> 6, l = t & 63, g = l >> 4, lc = l & 15;
  int wm = w >> 1, wn = w & 1;
  int axoff[4], bxoff[4];
  #pragma unroll
  for (int i = 0; i < 4; ++i) {
    int row = wm * 64 + i * 16 + lc;
    axoff[i] = row * 64 + ((g * 16) ^ ((lc & 3) << 4));
    row = wn * 64 + i * 16 + lc;
    bxoff[i] = row * 64 + ((g * 16) ^ ((lc & 3) << 4));
  }

  f32x4 acc[4][4] = {};

  for (int kt = 0; kt < KTOT / 32; ++kt) {
    int off = kt * 32;
    gl16(ga + off, la);
    gl16(ga2 + off, la2);
    gl16(gb + off, lb);
    gl16(gb2 + off, lb2);
    __syncthreads();
    us8 a[4], b[4];
    #pragma unroll
    for (int i = 0; i < 4; ++i) a[i] = *(const us8*)((const char*)Al + axoff[i]);
    #pragma unroll
    for (int j = 0; j < 4; ++j) b[j] = *(const us8*)((const char*)Bl + bxoff[j]);
    #pragma unroll
    for (int i = 0; i < 4; ++i)
      #pragma unroll
      for (int j = 0; j < 4; ++j)
        acc[i][j] = mfma16(a[i], b[j], acc[i][j]);
    __syncthreads();
  }

  float bv[4];
  #pragma unroll
  for (int jn = 0; jn < 4; ++jn) bv[jn] = bias[n0 + wn * 64 + jn * 16 + lc];
  #pragma unroll
  for (int i = 0; i < 4; ++i) {
    #pragma unroll
    for (int j = 0; j < 4; ++j) {
      int row = m0 + wm * 64 + i * 16 + g * 4 + j;
      float ssum = 0.f, ssq = 0.f;
      #pragma unroll
      for (int jn = 0; jn < 4; ++jn) {
        int col = n0 + wn * 64 + jn * 16 + lc;
        float v = acc[i][jn][j] + bv[jn];
        if (EPI == 1) v += resid[(size_t)row * 1024 + col];
        if (EPI == 0) outF[(size_t)row * 1024 + col] = f2bf(v);
        else          outO[(size_t)row * 1024 + col] = v;
        ssum += v; ssq += v * v;
      }
      #pragma unroll
      for (int msk = 1; msk < 16; msk <<= 1) {
        ssum += __shfl_xor(ssum, msk); ssq += __shfl_xor(ssq, msk);
      }
      if (lc == 0) { atomicAdd(&stats[row * 2], ssum); atomicAdd(&stats[row * 2 + 1], ssq); }
    }
  }
}

// ---------------- LN1 apply in place on fb (one wave per row) ----------------
__global__ __launch_bounds__(256) void k_ln1(
    unsigned short* __restrict__ fb, const float* __restrict__ stats1,
    const float* __restrict__ g, const float* __restrict__ b)
{
  int w = threadIdx.x >> 6, l = threadIdx.x & 63;
  int row = blockIdx.x * 4 + w;
  float sA = stats1[row * 2], sB = stats1[row * 2 + 1];
  float mu = sA * (1.f / 1024.f);
  float rs = rsqrtf(sB * (1.f / 1024.f) - mu * mu + 1e-5f);
  unsigned short* p = fb + (size_t)row * 1024 + l * 16;
  us8 v0 = *(const us8*)p;
  us8 v1 = *(const us8*)(p + 8);
  float gv[16], bv[16];
  #pragma unroll
  for (int q = 0; q < 4; ++q) {
    *(f32x4*)&gv[q * 4] = *(const f32x4*)(g + l * 16 + q * 4);
    *(f32x4*)&bv[q * 4] = *(const f32x4*)(b + l * 16 + q * 4);
  }
  us8 o0, o1;
  #pragma unroll
  for (int e = 0; e < 8; ++e) {
    o0[e] = f2bf((bf2f(v0[e]) - mu) * rs * gv[e] + bv[e]);
    o1[e] = f2bf((bf2f(v1[e]) - mu) * rs * gv[e + 8] + bv[e + 8]);
  }
  *(us8*)p = o0;
  *(us8*)(p + 8) = o1;
}

// ---------------- final LN2 in place on out f32 ----------------
__global__ __launch_bounds__(256) void k_ln2(
    float* __restrict__ out, const float* __restrict__ stats2,
    const float* __restrict__ ln2g, const float* __restrict__ ln2b)
{
  size_t idx = ((size_t)blockIdx.x * 256 + threadIdx.x) * 8;
  int row = (int)(idx >> 10);
  int col = (int)(idx & 1023);
  float sA = stats2[row * 2], sB = stats2[row * 2 + 1];
  float mu = sA * (1.f / 1024.f);
  float rs = rsqrtf(sB * (1.f / 1024.f) - mu * mu + 1e-5f);
  f32x4 t0 = *(const f32x4*)(out + idx);
  f32x4 t1 = *(const f32x4*)(out + idx + 4);
  f32x4 g0 = *(const f32x4*)(ln2g + col), g1 = *(const f32x4*)(ln2g + col + 4);
  f32x4 b0 = *(const f32x4*)(ln2b + col), b1v = *(const f32x4*)(ln2b + col + 4);
  f32x4 o0, o1;
  #pragma unroll
  for (int e = 0; e < 4; ++e) {
    o0[e] = (t0[e] - mu) * rs * g0[e] + b0[e];
    o1[e] = (t1[e] - mu) * rs * g1[e] + b1v[e];
  }
  *(f32x4*)(out + idx) = o0;
  *(f32x4*)(out + idx + 4) = o1;
}

extern "C" void kernel_launch(void* const* d_in, const int* in_sizes, int n_in,
                              void* d_out, int out_size, void* d_ws, size_t ws_size,
                              hipStream_t stream) {
  const float* x      = (const float*)d_in[0];
  const float* keys   = (const float*)d_in[1];
  const float* values = (const float*)d_in[2];
  const float* temp   = (const float*)d_in[3];
  const float* W1     = (const float*)d_in[4];
  const float* b1     = (const float*)d_in[5];
  const float* W2     = (const float*)d_in[6];
  const float* b2     = (const float*)d_in[7];
  const float* Wf     = (const float*)d_in[8];
  const float* bfp    = (const float*)d_in[9];
  const float* ln1g   = (const float*)d_in[10];
  const float* ln1b   = (const float*)d_in[11];
  const float* Wo     = (const float*)d_in[12];
  const float* bo     = (const float*)d_in[13];
  const float* ln2g   = (const float*)d_in[14];
  const float* ln2b   = (const float*)d_in[15];

  char* ws = (char*)d_ws;
  unsigned short* wft   = (unsigned short*)(ws + 0);
  unsigned short* wot   = (unsigned short*)(ws + 4194304);
  unsigned short* keysB = (unsigned short*)(ws + 6291456);
  unsigned short* valT  = (unsigned short*)(ws + 6553600);
  unsigned short* w1t   = (unsigned short*)(ws + 6815744);
  unsigned short* w2t   = (unsigned short*)(ws + 7077888);
  float* stats1         = (float*)(ws + 7110656);
  float* stats2         = (float*)(ws + 7372800);
  unsigned short* ww    = (unsigned short*)(ws + 7634944);
  float* partials       = (float*)(ws + 7634944 + 8388608);
  unsigned short* fb    = (unsigned short*)(ws + 7634944);  // aliases ww+partials (dead)

  unsigned short* xcat  = (unsigned short*)d_out;
  float* out            = (float*)d_out;
  float* newvals        = (float*)((char*)d_out + 134217728);

  k_prep<<<14400, 256, 0, stream>>>(keys, W1, W2, Wf, Wo, values,
                                    wft, wot, keysB, valT, w1t, w2t, stats1);
  k_castx<<<16384, 256, 0, stream>>>(x, xcat);
  k_attn<<<2048, 256, 0, stream>>>(xcat, keysB, valT, w1t, w2t, b1, b2, temp, xcat, ww);
  k_wv<<<256, 256, 0, stream>>>(xcat, ww, partials);
  k_red<<<512, 256, 0, stream>>>(values, partials, newvals);
  k_gemm<2048, 0><<<2048, 256, 0, stream>>>(xcat, wft, bfp, fb, nullptr, nullptr, stats1);
  k_ln1<<<8192, 256, 0, stream>>>(fb, stats1, ln1g, ln1b);
  k_gemm<1024, 1><<<2048, 256, 0, stream>>>(fb, wot, bo, nullptr, out, x, stats2);
  k_ln2<<<16384, 256, 0, stream>>>(out, stats2, ln2g, ln2b);
}